// Round 7
// baseline (1766.866 us; speedup 1.0000x reference)
//
#include <hip/hip_runtime.h>
#include <math.h>

#define H 1536
#define E 512
#define T 48
#define S 32
#define V 128
#define NB 256
#define BT 512      // 8 waves
#define JPB 6       // h indices per block
#define ROWS 24     // 4*JPB gate rows per block (per matrix)
#define RPW 3       // rows per wave per matrix
#define CHK 24      // floats per lane chunk (1536/64)
// dynamic LDS: whh2 (64 lanes * 145 float4) + one shared h-gather buffer
#define WHH2_B   (64 * 145 * 16)          // 148480
#define HBUF_B   (64 * 7 * 16)            // 7168
#define DYN_LDS  (WHH2_B + HBUF_B)        // 155648

typedef unsigned long long u64;

// ws layout (4-byte words):
//   [0, 32768)          logitt : u64[2][S*NB] tagged {f32 value, u32 gen}
//   [32768, 35840)      h2g    : float[2][H]        plain (uncached-atomic ops)
//   [36864, 135168)     candp  : float[2][S*H]      plain
//   [135168, 921600)    xw1g   : float[NB][V*ROWS]  block-private
#define H2_W    32768
#define CAND_W  36864
#define XW1_W   135168

__device__ __forceinline__ float sigf(float x) { return 1.0f / (1.0f + expf(-x)); }
__device__ __forceinline__ float wred(float acc) {
#pragma unroll
    for (int off = 32; off; off >>= 1) acc += __shfl_down(acc, off);
    return acc;
}

#define GLD(p)      __hip_atomic_load((p), __ATOMIC_RELAXED, __HIP_MEMORY_SCOPE_AGENT)
#define GST(p, v)   __hip_atomic_store((p), (v), __ATOMIC_RELAXED, __HIP_MEMORY_SCOPE_AGENT)
#define GLD64(p)    __hip_atomic_load((p), __ATOMIC_RELAXED, __HIP_MEMORY_SCOPE_AGENT)
#define GST64(p, v) __hip_atomic_store((p), (v), __ATOMIC_RELAXED, __HIP_MEMORY_SCOPE_AGENT)

__device__ __forceinline__ u64 pkf(float v, unsigned g) {
    return ((u64)g << 32) | (u64)__float_as_uint(v);
}
__device__ __forceinline__ float    pvf(u64 x) { return __uint_as_float((unsigned)x); }
__device__ __forceinline__ unsigned ptg(u64 x) { return (unsigned)(x >> 32); }

// Barrier-free round gate: the logit partials themselves carry {value, gen}.
// Round-k entry: each thread loads its 16 partial words (issued FIRST, so the
// transfer is in flight before any certification), re-polls only stale words,
// then one __syncthreads makes the union of observations block-wide.
// Transitive certification (same discipline proven in R1):
//   producer's round-k order = h2/cand plain stores -> __syncthreads (vmcnt
//   drain: stores acked at MALL) -> tagged partial store (gen k+2, LAST act).
//   Consumer observing tag(k+2) from block b => b's h2/cand(k) are at MALL
//   => later uncached reads see them. Entering round k+1 requires tags from
//   ALL 256 blocks => everyone finished their parity-(k&1) reads => end-of-
//   round-(k+1) overwrites of parity (k&1) race nobody (WAR safe).
__global__ __launch_bounds__(BT, 2) void nas_persist(
    const int* __restrict__ input_id, const float* __restrict__ emb,
    const float* __restrict__ Wih1, const float* __restrict__ Whh1,
    const float* __restrict__ bih1, const float* __restrict__ bhh1,
    const float* __restrict__ Wih2, const float* __restrict__ Whh2,
    const float* __restrict__ bih2, const float* __restrict__ bhh2,
    const float* __restrict__ Wout, const float* __restrict__ bout,
    float* __restrict__ out, float* __restrict__ ws)
{
    const int b = blockIdx.x, tid = threadIdx.x;
    const int wave = tid >> 6, lane = tid & 63;

    u64* logitt = (u64*)ws;               // [parity*S*NB + s*NB + b]
    float* h2gp[2]  = { ws + H2_W,   ws + H2_W + H };
    float* candp[2] = { ws + CAND_W, ws + CAND_W + S * H };
    float* xw1g = ws + XW1_W + (size_t)b * (V * ROWS);

    extern __shared__ char dyn_lds[];
    float4* whh2s = (float4*)dyn_lds;                 // [lane*145 + row*6 + j]
    float*  hbuf  = (float*)(dyn_lds + WHH2_B);       // chunked, stride 28

    __shared__ float gacc1[ROWS], g2f[ROWS], bsum2[ROWS], zlog[S], h2f[JPB];
    __shared__ float c1s[JPB], c2s[JPB], c1cand[S * JPB];
    __shared__ int   xid_s, pred_s;

    // ---------------- prologue ----------------
    if (tid < JPB) { c2s[tid] = 0.f; GST(h2gp[0] + b * JPB + tid, 0.f); }
    if (tid < ROWS) {
        int r = (tid / JPB) * H + b * JPB + (tid % JPB);
        bsum2[tid] = bih2[r] + bhh2[r];
    }
    if (tid == 0) xid_s = *input_id;

    // ---- xw1 table -> global ws (uses whh2s region as emb staging) ----
    {
        const int k0 = wave * RPW;
        float4 wiA[RPW], wiB[RPW];
        float  bs[RPW];
#pragma unroll
        for (int i = 0; i < RPW; ++i) {
            int k = k0 + i;
            int r = (k / JPB) * H + b * JPB + (k % JPB);
            const float4* w = (const float4*)(Wih1 + (size_t)r * E);
            wiA[i] = w[lane]; wiB[i] = w[lane + 64];
            bs[i]  = bih1[r] + bhh1[r];
        }
        float4* stage = (float4*)dyn_lds;             // 2048 f4 = 32 KB
        for (int ch = 0; ch < 8; ++ch) {
            const float4* src = (const float4*)(emb + (size_t)ch * 16 * E);
            for (int m = tid; m < 2048; m += BT) stage[m] = src[m];
            __syncthreads();
            for (int vv = 0; vv < 16; ++vv) {
                float4 ea = stage[vv * 128 + lane];
                float4 eb = stage[vv * 128 + 64 + lane];
#pragma unroll
                for (int i = 0; i < RPW; ++i) {
                    float a = wiA[i].x * ea.x + wiA[i].y * ea.y + wiA[i].z * ea.z + wiA[i].w * ea.w
                            + wiB[i].x * eb.x + wiB[i].y * eb.y + wiB[i].z * eb.z + wiB[i].w * eb.w;
                    a = wred(a);
                    if (lane == 0) xw1g[(ch * 16 + vv) * ROWS + (k0 + i)] = a + bs[i];
                }
            }
            __syncthreads();
        }
    }

    // ---- Whh2 -> LDS (lane-chunked, odd-f4 stride 145) ----
    for (int k = 0; k < ROWS; ++k) {
        int r = (k / JPB) * H + b * JPB + (k % JPB);
        const float4* src = (const float4*)(Whh2 + (size_t)r * H);
        if (tid < 384) {
            int l = tid / 6, j = tid % 6;
            whh2s[l * 145 + k * 6 + j] = src[tid];
        }
    }
    __syncthreads();

    // ---- Whh1 + Wih2 rows -> registers ----
    float w1[RPW][CHK], w2[RPW][CHK];
#pragma unroll
    for (int i = 0; i < RPW; ++i) {
        int k = wave * RPW + i;
        int r = (k / JPB) * H + b * JPB + (k % JPB);
        const float4* p1 = (const float4*)(Whh1 + (size_t)r * H) + lane * 6;
        const float4* p2 = (const float4*)(Wih2 + (size_t)r * H) + lane * 6;
#pragma unroll
        for (int j = 0; j < 6; ++j) {
            float4 v1 = p1[j], v2 = p2[j];
            w1[i][4 * j + 0] = v1.x; w1[i][4 * j + 1] = v1.y;
            w1[i][4 * j + 2] = v1.z; w1[i][4 * j + 3] = v1.w;
            w2[i][4 * j + 0] = v2.x; w2[i][4 * j + 1] = v2.y;
            w2[i][4 * j + 2] = v2.z; w2[i][4 * j + 3] = v2.w;
        }
    }
    __syncthreads();

    // ---- h1(0) from xid(0)=input_id; publish candidate slot 0, parity 0 ----
    if (tid < JPB) {
        const float* xr = xw1g + (size_t)xid_s * ROWS;
        float gi = xr[tid], gg = xr[2 * JPB + tid], go = xr[3 * JPB + tid];
        float cn = sigf(gi) * tanhf(gg);
        c1s[tid] = cn;
        GST(candp[0] + b * JPB + tid, sigf(go) * tanhf(cn));   // slot 0, parity 0
    }
    __syncthreads();                       // drain h2/cand publishes (vmcnt 0)
    // prologue-done tags: parity 0, gen 1, values 0 (round 0 skips the reduce)
    if (wave == 0 && lane < S)
        GST64(logitt + lane * NB + b, pkf(0.f, 1u));

    // precomputed hbuf scatter maps (stride-28 chunked layout)
    const int m0 = (tid / CHK) * 28 + (tid % CHK);
    const int m1 = ((tid + 512) / CHK) * 28 + ((tid + 512) % CHK);
    const int m2 = ((tid + 1024) / CHK) * 28 + ((tid + 1024) % CHK);

    // ---------------- main loop: zero barriers, tag-gated rounds ----------------
    for (int k = 0; k <= T; ++k) {
        const unsigned expg = (unsigned)(k + 1);

        // 1) tagged partial loads: FIRST in the vmcnt FIFO (in flight before
        //    any certification); laggard-only re-poll afterward
        u64 pv[16];
        const u64* lp = logitt + (size_t)(k & 1) * (S * NB)
                        + (tid >> 4) * NB + (tid & 15) * 16;
#pragma unroll
        for (int i = 0; i < 16; ++i) pv[i] = GLD64(lp + i);

        // 2) cold Wout slice (plain cached; constant input, safe anytime)
        float wcol[JPB];
        if (k < T && wave == 0 && lane < S) {
            const float* wp = Wout + ((size_t)k * S + lane) * H + b * JPB;
#pragma unroll
            for (int j = 0; j < JPB; ++j) wcol[j] = wp[j];
        }

        // 3) poll: re-load only stale words
        for (;;) {
            bool ok = true;
#pragma unroll
            for (int i = 0; i < 16; ++i) ok &= (ptg(pv[i]) >= expg);
            if (ok) break;
            __builtin_amdgcn_s_sleep(1);
#pragma unroll
            for (int i = 0; i < 16; ++i)
                if (ptg(pv[i]) < expg) pv[i] = GLD64(lp + i);
        }
        __syncthreads();                   // union of tag observations block-wide

        // 4) h2(k-1) gather: certified now; RTT hides under reduce/argmax
        const float* h2src = h2gp[k & 1];
        float u0 = GLD(h2src + tid);
        float u1 = GLD(h2src + tid + 512);
        float u2 = GLD(h2src + tid + 1024);

        // logits(k-1): fixed-order reduce (bitwise identical to R1 and across blocks)
        if (k > 0) {
            float acc = 0.f;
#pragma unroll
            for (int i = 0; i < 16; ++i) acc += pvf(pv[i]);
#pragma unroll
            for (int off = 8; off; off >>= 1) acc += __shfl_down(acc, off, 16);
            if ((tid & 15) == 0)
                zlog[tid >> 4] = acc + bout[(size_t)(k - 1) * S + (tid >> 4)];
        }
        __syncthreads();
        if (k > 0) {
            if (wave == 0) {
                float z = (lane < S) ? zlog[lane] : -1e30f;
                float v = z; int idx = (lane < S) ? lane : 9999;
#pragma unroll
                for (int off = 32; off; off >>= 1) {
                    float ov = __shfl_xor(v, off); int oi = __shfl_xor(idx, off);
                    if (ov > v || (ov == v && oi < idx)) { v = ov; idx = oi; }
                }
                float e = (lane < S) ? expf(z - v) : 0.f;
#pragma unroll
                for (int off = 32; off; off >>= 1) e += __shfl_xor(e, off);
                if (lane == 0) pred_s = idx;
                if (b == 0 && lane < S) out[(size_t)(k - 1) * S + lane] = z - v - logf(e);
            }
            __syncthreads();
        }
        if (k == T) return;                // out[T-1] written; done
        const int psel = (k > 0) ? pred_s : 0;
        if (k > 0 && tid < JPB) c1s[tid] = c1cand[psel * JPB + tid];

        // issue h1 gather NOW; h2 LDS hop + gaccH hide its latency
        const float* h1src = candp[k & 1] + (size_t)psel * H;
        float t0 = GLD(h1src + tid);
        float t1 = GLD(h1src + tid + 512);
        float t2 = GLD(h1src + tid + 1024);

        hbuf[m0] = u0; hbuf[m1] = u1; hbuf[m2] = u2;   // h2 -> LDS
        __syncthreads();
        float h2c[CHK];
        {
            const float4* hp = (const float4*)hbuf + lane * 7;
#pragma unroll
            for (int j = 0; j < 6; ++j) {
                float4 v = hp[j];
                h2c[4 * j + 0] = v.x; h2c[4 * j + 1] = v.y;
                h2c[4 * j + 2] = v.z; h2c[4 * j + 3] = v.w;
            }
        }
        // Whh2 @ h2(k-1) dots (registers; h1 gather in flight underneath)
        float ahv[RPW];
#pragma unroll
        for (int i = 0; i < RPW; ++i) {
            int kk = wave * RPW + i;
            const float4* wp = whh2s + lane * 145 + kk * 6;
            float ah = 0.f;
#pragma unroll
            for (int j = 0; j < 6; ++j) {
                float4 v = wp[j];
                ah += v.x * h2c[4 * j + 0] + v.y * h2c[4 * j + 1]
                    + v.z * h2c[4 * j + 2] + v.w * h2c[4 * j + 3];
            }
            ahv[i] = wred(ah);             // valid at lane 0
        }
        __syncthreads();                   // hbuf free for h1
        hbuf[m0] = t0; hbuf[m1] = t1; hbuf[m2] = t2;
        __syncthreads();
        float h1c[CHK];
        {
            const float4* hp = (const float4*)hbuf + lane * 7;
#pragma unroll
            for (int j = 0; j < 6; ++j) {
                float4 v = hp[j];
                h1c[4 * j + 0] = v.x; h1c[4 * j + 1] = v.y;
                h1c[4 * j + 2] = v.z; h1c[4 * j + 3] = v.w;
            }
        }
        // D1: Whh1 @ h1(k), Wih2 @ h1(k) (register weights)
        float a1[RPW], a2[RPW];
#pragma unroll
        for (int i = 0; i < RPW; ++i) { a1[i] = 0.f; a2[i] = 0.f; }
#pragma unroll
        for (int kk = 0; kk < CHK; ++kk) {
            float h = h1c[kk];
#pragma unroll
            for (int i = 0; i < RPW; ++i) {
                a1[i] += w1[i][kk] * h;
                a2[i] += w2[i][kk] * h;
            }
        }
#pragma unroll
        for (int i = 0; i < RPW; ++i) {
            int kk = wave * RPW + i;
            float s1 = wred(a1[i]);
            float s2 = wred(a2[i]);
            if (lane == 0) {
                gacc1[kk] = s1;
                g2f[kk]   = s2 + ahv[i] + bsum2[kk];
            }
        }
        __syncthreads();

        // P2: h2(k) fragment -> publish to parity (k+1)&1
        if (tid < JPB) {
            float gi = g2f[tid],           gf = g2f[JPB + tid];
            float gg = g2f[2 * JPB + tid], go = g2f[3 * JPB + tid];
            float cn = sigf(gf) * c2s[tid] + sigf(gi) * tanhf(gg);
            c2s[tid] = cn;
            float hn = sigf(go) * tanhf(cn);
            h2f[tid] = hn;
            GST(h2gp[(k + 1) & 1] + b * JPB + tid, hn);
        }
        // candidates for h1(k+1): all 32 possible preds; publish fragments
        if (tid < S * JPB) {
            int p = tid / JPB, j = tid % JPB;
            const float* xr = xw1g + (size_t)((k & 3) * S + p) * ROWS;
            float gi = gacc1[j]           + xr[j];
            float gf = gacc1[JPB + j]     + xr[JPB + j];
            float gg = gacc1[2 * JPB + j] + xr[2 * JPB + j];
            float go = gacc1[3 * JPB + j] + xr[3 * JPB + j];
            float cn = sigf(gf) * c1s[j] + sigf(gi) * tanhf(gg);
            c1cand[tid] = cn;
            GST(candp[(k + 1) & 1] + (size_t)p * H + b * JPB + j,
                sigf(go) * tanhf(cn));
        }
        __syncthreads();                   // h2f visible + h2/cand stores DRAINED
        // tagged partial logits(k): flag+payload fused; LAST act of round k
        if (wave == 0 && lane < S) {
            float p = 0.f;
#pragma unroll
            for (int j = 0; j < JPB; ++j) p += wcol[j] * h2f[j];
            GST64(logitt + (size_t)((k + 1) & 1) * (S * NB) + lane * NB + b,
                  pkf(p, (unsigned)(k + 2)));
        }
    }
}

extern "C" void kernel_launch(void* const* d_in, const int* in_sizes, int n_in,
                              void* d_out, int out_size, void* d_ws, size_t ws_size,
                              hipStream_t stream) {
    const int*   input_id = (const int*)d_in[0];
    const float* emb  = (const float*)d_in[1];
    const float* Wih1 = (const float*)d_in[2];
    const float* Whh1 = (const float*)d_in[3];
    const float* bih1 = (const float*)d_in[4];
    const float* bhh1 = (const float*)d_in[5];
    const float* Wih2 = (const float*)d_in[6];
    const float* Whh2 = (const float*)d_in[7];
    const float* bih2 = (const float*)d_in[8];
    const float* bhh2 = (const float*)d_in[9];
    const float* Wout = (const float*)d_in[10];
    const float* bout = (const float*)d_in[11];
    float* out = (float*)d_out;
    float* ws  = (float*)d_ws;

    // tagged partial region must restart below gen 1 each dispatch
    hipMemsetAsync(d_ws, 0, 2 * S * NB * sizeof(u64), stream);

    void* args[] = { (void*)&input_id, (void*)&emb,
                     (void*)&Wih1, (void*)&Whh1, (void*)&bih1, (void*)&bhh1,
                     (void*)&Wih2, (void*)&Whh2, (void*)&bih2, (void*)&bhh2,
                     (void*)&Wout, (void*)&bout, (void*)&out, (void*)&ws };
    hipLaunchCooperativeKernel((void*)nas_persist, dim3(NB), dim3(BT), args,
                               DYN_LDS, stream);
}

// Round 8
// 1145.682 us; speedup vs baseline: 1.5422x; 1.5422x over previous
//
#include <hip/hip_runtime.h>
#include <math.h>

#define H 1536
#define E 512
#define T 48
#define S 32
#define V 128
#define NB 256
#define BT 512      // 8 waves
#define JPB 6       // h indices per block
#define ROWS 24     // 4*JPB gate rows per block (per matrix)
#define RPW 3       // rows per wave per matrix
#define CHK 24      // floats per lane chunk (1536/64)
// dynamic LDS: whh2 (64 lanes * 145 float4) + one shared h-gather buffer
#define WHH2_B   (64 * 145 * 16)          // 148480
#define HBUF_B   (64 * 7 * 16)            // 7168
#define DYN_LDS  (WHH2_B + HBUF_B)        // 155648

__device__ __forceinline__ float sigf(float x) { return 1.0f / (1.0f + expf(-x)); }
__device__ __forceinline__ float wred(float acc) {
#pragma unroll
    for (int off = 32; off; off >>= 1) acc += __shfl_down(acc, off);
    return acc;
}

#define GLD(p)    __hip_atomic_load((p), __ATOMIC_RELAXED, __HIP_MEMORY_SCOPE_AGENT)
#define GST(p, v) __hip_atomic_store((p), (v), __ATOMIC_RELAXED, __HIP_MEMORY_SCOPE_AGENT)

// All-poll barrier: every block arrives (flag store), every block's wave 0
// polls all 256 arrival flags itself. Empirically the best of 8 tested
// sync structures (R0-R7): narrow poll (64 threads x 4 words), plain
// uncached payloads, no central phase, no fences, no tags.
// Data-before-flag: __syncthreads drains vmcnt before s_barrier. Parity
// double-buffering of all shared data makes "proceed on seeing all
// arrivals" safe: a block that races ahead writes only the opposite
// parity, and re-reads of a parity are gated by the next generation.
__device__ __forceinline__ void gbar(unsigned* flags, unsigned& gen) {
    __syncthreads();
    gen++;
    if (threadIdx.x == 0) GST(&flags[blockIdx.x * 16], gen);
    if (threadIdx.x < 64) {
        const int i0 = threadIdx.x * 4;
        for (;;) {
            unsigned a0 = GLD(&flags[(i0 + 0) * 16]);
            unsigned a1 = GLD(&flags[(i0 + 1) * 16]);
            unsigned a2 = GLD(&flags[(i0 + 2) * 16]);
            unsigned a3 = GLD(&flags[(i0 + 3) * 16]);
            bool ok = (a0 >= gen) && (a1 >= gen) && (a2 >= gen) && (a3 >= gen);
            if (__all(ok)) break;
            __builtin_amdgcn_s_sleep(1);
        }
    }
    __syncthreads();
}

__global__ void init_kernel(unsigned* u) {
    for (int i = threadIdx.x; i < 8192; i += 256) u[i] = 0u;   // legacy rel + flags
}

// ws words: [0..4096) legacy rel (unused) | [4096..8192) flags |
//   [8192) h2g parity0 [H] | parity1 [H] |
//   [16384) cand parity0 [S*H] | parity1 [S*H] |
//   [114688) xw1g: NB * V * 24 |
//   [901120) logitp: parity0 [S*NB] | parity1 [S*NB]
__global__ __launch_bounds__(BT, 2) void nas_persist(
    const int* __restrict__ input_id, const float* __restrict__ emb,
    const float* __restrict__ Wih1, const float* __restrict__ Whh1,
    const float* __restrict__ bih1, const float* __restrict__ bhh1,
    const float* __restrict__ Wih2, const float* __restrict__ Whh2,
    const float* __restrict__ bih2, const float* __restrict__ bhh2,
    const float* __restrict__ Wout, const float* __restrict__ bout,
    float* __restrict__ out, float* __restrict__ ws)
{
    const int b = blockIdx.x, tid = threadIdx.x;
    const int wave = tid >> 6, lane = tid & 63;

    unsigned* flags = (unsigned*)ws + 4096;
    float* h2gp[2]  = { ws + 8192, ws + 8192 + H };
    float* candp[2] = { ws + 16384, ws + 16384 + S * H };
    float* xw1g = ws + 114688 + (size_t)b * (V * ROWS);
    float* logitp = ws + 901120;

    extern __shared__ char dyn_lds[];
    float4* whh2s = (float4*)dyn_lds;                 // [lane*145 + row*6 + j]
    float*  hbuf  = (float*)(dyn_lds + WHH2_B);       // chunked, stride 28

    __shared__ float gacc1[ROWS], g2f[ROWS], bsum2[ROWS], zlog[S], h2f[JPB];
    __shared__ float c1s[JPB], c2s[JPB], c1cand[S * JPB];
    __shared__ int   xid_s, pred_s;

    unsigned gen = 0;

    // ---------------- prologue ----------------
    if (tid < JPB) { c2s[tid] = 0.f; GST(h2gp[0] + b * JPB + tid, 0.f); }
    if (tid < ROWS) {
        int r = (tid / JPB) * H + b * JPB + (tid % JPB);
        bsum2[tid] = bih2[r] + bhh2[r];
    }
    if (tid == 0) xid_s = *input_id;

    // ---- xw1 table -> global ws (uses whh2s region as emb staging) ----
    {
        const int k0 = wave * RPW;
        float4 wiA[RPW], wiB[RPW];
        float  bs[RPW];
#pragma unroll
        for (int i = 0; i < RPW; ++i) {
            int k = k0 + i;
            int r = (k / JPB) * H + b * JPB + (k % JPB);
            const float4* w = (const float4*)(Wih1 + (size_t)r * E);
            wiA[i] = w[lane]; wiB[i] = w[lane + 64];
            bs[i]  = bih1[r] + bhh1[r];
        }
        float4* stage = (float4*)dyn_lds;             // 2048 f4 = 32 KB
        for (int ch = 0; ch < 8; ++ch) {
            const float4* src = (const float4*)(emb + (size_t)ch * 16 * E);
            for (int m = tid; m < 2048; m += BT) stage[m] = src[m];
            __syncthreads();
            for (int vv = 0; vv < 16; ++vv) {
                float4 ea = stage[vv * 128 + lane];
                float4 eb = stage[vv * 128 + 64 + lane];
#pragma unroll
                for (int i = 0; i < RPW; ++i) {
                    float a = wiA[i].x * ea.x + wiA[i].y * ea.y + wiA[i].z * ea.z + wiA[i].w * ea.w
                            + wiB[i].x * eb.x + wiB[i].y * eb.y + wiB[i].z * eb.z + wiB[i].w * eb.w;
                    a = wred(a);
                    if (lane == 0) xw1g[(ch * 16 + vv) * ROWS + (k0 + i)] = a + bs[i];
                }
            }
            __syncthreads();
        }
    }

    // ---- Whh2 -> LDS (lane-chunked, odd-f4 stride 145) ----
    for (int k = 0; k < ROWS; ++k) {
        int r = (k / JPB) * H + b * JPB + (k % JPB);
        const float4* src = (const float4*)(Whh2 + (size_t)r * H);
        if (tid < 384) {
            int l = tid / 6, j = tid % 6;
            whh2s[l * 145 + k * 6 + j] = src[tid];
        }
    }
    __syncthreads();

    // ---- Whh1 + Wih2 rows -> registers ----
    float w1[RPW][CHK], w2[RPW][CHK];
#pragma unroll
    for (int i = 0; i < RPW; ++i) {
        int k = wave * RPW + i;
        int r = (k / JPB) * H + b * JPB + (k % JPB);
        const float4* p1 = (const float4*)(Whh1 + (size_t)r * H) + lane * 6;
        const float4* p2 = (const float4*)(Wih2 + (size_t)r * H) + lane * 6;
#pragma unroll
        for (int j = 0; j < 6; ++j) {
            float4 v1 = p1[j], v2 = p2[j];
            w1[i][4 * j + 0] = v1.x; w1[i][4 * j + 1] = v1.y;
            w1[i][4 * j + 2] = v1.z; w1[i][4 * j + 3] = v1.w;
            w2[i][4 * j + 0] = v2.x; w2[i][4 * j + 1] = v2.y;
            w2[i][4 * j + 2] = v2.z; w2[i][4 * j + 3] = v2.w;
        }
    }
    __syncthreads();

    // ---- h1(0) from xid(0)=input_id (gacc1=0, c1(-1)=0); publish to slot 0 ----
    if (tid < JPB) {
        const float* xr = xw1g + (size_t)xid_s * ROWS;
        float gi = xr[tid], gg = xr[2 * JPB + tid], go = xr[3 * JPB + tid];
        float cn = sigf(gi) * tanhf(gg);
        c1s[tid] = cn;
        GST(candp[0] + b * JPB + tid, sigf(go) * tanhf(cn));   // slot 0, parity 0
    }
    gbar(flags, gen);

    // precomputed hbuf scatter maps (stride-28 chunked layout)
    const int m0 = (tid / CHK) * 28 + (tid % CHK);
    const int m1 = ((tid + 512) / CHK) * 28 + ((tid + 512) % CHK);
    const int m2 = ((tid + 1024) / CHK) * 28 + ((tid + 1024) % CHK);

    // ---------------- main loop: ONE barrier per round ----------------
    for (int k = 0; k <= T; ++k) {
        // ---- phase 0: issue all independent loads early ----
        float wcol[JPB];                       // Wout column slice for THIS round's
        if (k < T && wave == 0 && lane < S) {  // producer-side partial logits (tail)
            const float* wp = Wout + ((size_t)k * S + lane) * H + b * JPB;
#pragma unroll
            for (int j = 0; j < JPB; ++j) wcol[j] = wp[j];
        }
        const float* h2src = h2gp[k & 1];
        float u0 = GLD(h2src + tid);
        float u1 = GLD(h2src + tid + 512);
        float u2 = GLD(h2src + tid + 1024);

        // logits(k-1) = deterministic fixed-order tree over 256 partials
        if (k > 0) {
            const float* lp = logitp + (size_t)(k & 1) * (S * NB)
                              + (tid >> 4) * NB + (tid & 15) * 16;
            float acc = 0.f;
#pragma unroll
            for (int i = 0; i < 16; ++i) acc += GLD(lp + i);
#pragma unroll
            for (int off = 8; off; off >>= 1) acc += __shfl_down(acc, off, 16);
            if ((tid & 15) == 0)
                zlog[tid >> 4] = acc + bout[(size_t)(k - 1) * S + (tid >> 4)];
        }
        __syncthreads();
        if (k > 0) {
            if (wave == 0) {
                float z = (lane < S) ? zlog[lane] : -1e30f;
                float v = z; int idx = (lane < S) ? lane : 9999;
#pragma unroll
                for (int off = 32; off; off >>= 1) {
                    float ov = __shfl_xor(v, off); int oi = __shfl_xor(idx, off);
                    if (ov > v || (ov == v && oi < idx)) { v = ov; idx = oi; }
                }
                float e = (lane < S) ? expf(z - v) : 0.f;
#pragma unroll
                for (int off = 32; off; off >>= 1) e += __shfl_xor(e, off);
                if (lane == 0) pred_s = idx;
                if (b == 0 && lane < S) out[(size_t)(k - 1) * S + lane] = z - v - logf(e);
            }
            __syncthreads();
        }
        if (k == T) return;                    // out[T-1] written; done
        const int psel = (k > 0) ? pred_s : 0;
        if (k > 0 && tid < JPB) c1s[tid] = c1cand[psel * JPB + tid];   // c1(k) select

        // ---- phase 1: issue h1 gather NOW; h2 LDS hop + gaccH hide its latency ----
        const float* h1src = candp[k & 1] + (size_t)psel * H;
        float t0 = GLD(h1src + tid);
        float t1 = GLD(h1src + tid + 512);
        float t2 = GLD(h1src + tid + 1024);

        hbuf[m0] = u0; hbuf[m1] = u1; hbuf[m2] = u2;   // h2 -> LDS
        __syncthreads();
        float h2c[CHK];
        {
            const float4* hp = (const float4*)hbuf + lane * 7;
#pragma unroll
            for (int j = 0; j < 6; ++j) {
                float4 v = hp[j];
                h2c[4 * j + 0] = v.x; h2c[4 * j + 1] = v.y;
                h2c[4 * j + 2] = v.z; h2c[4 * j + 3] = v.w;
            }
        }
        // Whh2 @ h2(k-1) dots (registers; h1 gather in flight underneath)
        float ahv[RPW];
#pragma unroll
        for (int i = 0; i < RPW; ++i) {
            int kk = wave * RPW + i;
            const float4* wp = whh2s + lane * 145 + kk * 6;
            float ah = 0.f;
#pragma unroll
            for (int j = 0; j < 6; ++j) {
                float4 v = wp[j];
                ah += v.x * h2c[4 * j + 0] + v.y * h2c[4 * j + 1]
                    + v.z * h2c[4 * j + 2] + v.w * h2c[4 * j + 3];
            }
            ahv[i] = wred(ah);                 // valid at lane 0
        }
        __syncthreads();                       // hbuf free for h1
        hbuf[m0] = t0; hbuf[m1] = t1; hbuf[m2] = t2;
        __syncthreads();
        float h1c[CHK];
        {
            const float4* hp = (const float4*)hbuf + lane * 7;
#pragma unroll
            for (int j = 0; j < 6; ++j) {
                float4 v = hp[j];
                h1c[4 * j + 0] = v.x; h1c[4 * j + 1] = v.y;
                h1c[4 * j + 2] = v.z; h1c[4 * j + 3] = v.w;
            }
        }
        // D1: Whh1 @ h1(k), Wih2 @ h1(k) (register weights)
        float a1[RPW], a2[RPW];
#pragma unroll
        for (int i = 0; i < RPW; ++i) { a1[i] = 0.f; a2[i] = 0.f; }
#pragma unroll
        for (int kk = 0; kk < CHK; ++kk) {
            float h = h1c[kk];
#pragma unroll
            for (int i = 0; i < RPW; ++i) {
                a1[i] += w1[i][kk] * h;
                a2[i] += w2[i][kk] * h;
            }
        }
#pragma unroll
        for (int i = 0; i < RPW; ++i) {
            int kk = wave * RPW + i;
            float s1 = wred(a1[i]);
            float s2 = wred(a2[i]);
            if (lane == 0) {
                gacc1[kk] = s1;
                g2f[kk]   = s2 + ahv[i] + bsum2[kk];
            }
        }
        __syncthreads();

        // P2: h2(k) fragment -> publish to parity (k+1)&1 (+ keep in LDS for partials)
        if (tid < JPB) {
            float gi = g2f[tid],           gf = g2f[JPB + tid];
            float gg = g2f[2 * JPB + tid], go = g2f[3 * JPB + tid];
            float cn = sigf(gf) * c2s[tid] + sigf(gi) * tanhf(gg);
            c2s[tid] = cn;
            float hn = sigf(go) * tanhf(cn);
            h2f[tid] = hn;
            GST(h2gp[(k + 1) & 1] + b * JPB + tid, hn);
        }
        // candidates for h1(k+1): all 32 possible preds; publish fragments
        if (tid < S * JPB) {
            int p = tid / JPB, j = tid % JPB;
            const float* xr = xw1g + (size_t)((k & 3) * S + p) * ROWS;
            float gi = gacc1[j]           + xr[j];
            float gf = gacc1[JPB + j]     + xr[JPB + j];
            float gg = gacc1[2 * JPB + j] + xr[2 * JPB + j];
            float go = gacc1[3 * JPB + j] + xr[3 * JPB + j];
            float cn = sigf(gf) * c1s[j] + sigf(gi) * tanhf(gg);
            c1cand[tid] = cn;
            GST(candp[(k + 1) & 1] + (size_t)p * H + b * JPB + j,
                sigf(go) * tanhf(cn));
        }
        __syncthreads();                       // h2f visible to wave 0
        // producer-side partial logits(k): this block's 6-column contribution
        if (wave == 0 && lane < S) {
            float p = 0.f;
#pragma unroll
            for (int j = 0; j < JPB; ++j) p += wcol[j] * h2f[j];
            GST(logitp + (size_t)((k + 1) & 1) * (S * NB) + lane * NB + b, p);
        }
        gbar(flags, gen);
    }
}

extern "C" void kernel_launch(void* const* d_in, const int* in_sizes, int n_in,
                              void* d_out, int out_size, void* d_ws, size_t ws_size,
                              hipStream_t stream) {
    const int*   input_id = (const int*)d_in[0];
    const float* emb  = (const float*)d_in[1];
    const float* Wih1 = (const float*)d_in[2];
    const float* Whh1 = (const float*)d_in[3];
    const float* bih1 = (const float*)d_in[4];
    const float* bhh1 = (const float*)d_in[5];
    const float* Wih2 = (const float*)d_in[6];
    const float* Whh2 = (const float*)d_in[7];
    const float* bih2 = (const float*)d_in[8];
    const float* bhh2 = (const float*)d_in[9];
    const float* Wout = (const float*)d_in[10];
    const float* bout = (const float*)d_in[11];
    float* out = (float*)d_out;
    float* ws  = (float*)d_ws;

    init_kernel<<<1, 256, 0, stream>>>((unsigned*)ws);

    void* args[] = { (void*)&input_id, (void*)&emb,
                     (void*)&Wih1, (void*)&Whh1, (void*)&bih1, (void*)&bhh1,
                     (void*)&Wih2, (void*)&Whh2, (void*)&bih2, (void*)&bhh2,
                     (void*)&Wout, (void*)&bout, (void*)&out, (void*)&ws };
    hipLaunchCooperativeKernel((void*)nas_persist, dim3(NB), dim3(BT), args,
                               DYN_LDS, stream);
}

// Round 9
// 997.633 us; speedup vs baseline: 1.7711x; 1.1484x over previous
//
#include <hip/hip_runtime.h>
#include <math.h>

#define H 1536
#define E 512
#define T 48
#define S 32
#define V 128
#define NB 256
#define BT 512      // 8 waves
#define JPB 6       // h indices per block
#define ROWS 24     // 4*JPB gate rows per block (per matrix)
#define RPW 3       // rows per wave per matrix
#define CHK 24      // floats per lane chunk (1536/64)
// dynamic LDS: whh2 (64 lanes * 145 float4) + one shared h-gather buffer
#define WHH2_B   (64 * 145 * 16)          // 148480
#define HBUF_B   (64 * 7 * 16)            // 7168
#define DYN_LDS  (WHH2_B + HBUF_B)        // 155648

// ws layout (4-byte words):
//   [0..4096)            legacy (zeroed)
//   [4096..8192)         flags : 256 arrival flags, 64B stride (uncached atomics)
//   [8192..83456)        h2g   : float[T+1][H]     round-indexed, line-aligned
//                                (producer GST write-through; consumer PLAIN
//                                cached loads -- virgin address per round)
//   [83968..485376)      logitp: float[T+1][S*NB]  round-indexed, same scheme
//   [485376..583680)     candp : float[2][S*H]     2-parity, uncached path
//   [583680..1370112)    xw1g  : float[NB][V*ROWS] block-private
#define H2_W    8192
#define LOG_W   83968
#define CAND_W  485376
#define XW1_W   583680

__device__ __forceinline__ float sigf(float x) { return 1.0f / (1.0f + expf(-x)); }
__device__ __forceinline__ float wred(float acc) {
#pragma unroll
    for (int off = 32; off; off >>= 1) acc += __shfl_down(acc, off);
    return acc;
}

#define GLD(p)    __hip_atomic_load((p), __ATOMIC_RELAXED, __HIP_MEMORY_SCOPE_AGENT)
#define GST(p, v) __hip_atomic_store((p), (v), __ATOMIC_RELAXED, __HIP_MEMORY_SCOPE_AGENT)

// All-poll barrier (R1, empirically best of 8 sync structures R0-R7).
// Data-before-flag: __syncthreads drains vmcnt before the flag store.
__device__ __forceinline__ void gbar(unsigned* flags, unsigned& gen) {
    __syncthreads();
    gen++;
    if (threadIdx.x == 0) GST(&flags[blockIdx.x * 16], gen);
    if (threadIdx.x < 64) {
        const int i0 = threadIdx.x * 4;
        for (;;) {
            unsigned a0 = GLD(&flags[(i0 + 0) * 16]);
            unsigned a1 = GLD(&flags[(i0 + 1) * 16]);
            unsigned a2 = GLD(&flags[(i0 + 2) * 16]);
            unsigned a3 = GLD(&flags[(i0 + 3) * 16]);
            bool ok = (a0 >= gen) && (a1 >= gen) && (a2 >= gen) && (a3 >= gen);
            if (__all(ok)) break;
            __builtin_amdgcn_s_sleep(1);
        }
    }
    __syncthreads();
}

__global__ void init_kernel(unsigned* u) {
    for (int i = threadIdx.x; i < 8192; i += 256) u[i] = 0u;   // legacy + flags
}

// R1 structure with CACHED broadcast reads:
//  - h2g / logitp are indexed by ROUND (slot k), never reused in a dispatch.
//    Producers publish with agent-scope stores (write-through to MALL, the
//    proven mechanism of R0-R8). Consumers read with PLAIN cached loads:
//    caches are invalidated at dispatch start, and the first-ever touch of
//    a slot happens after the gbar that follows the producers' drained
//    stores, so the cold L2 miss fetches fresh MALL data. Within an XCD the
//    32 blocks then share ONE L2 fill per line -- MALL serves 8 requests
//    per broadcast line instead of 256 (the per-line queueing that the
//    R0-R8 uncached path paid on every round).
//  - cand stays 2-parity + uncached GLD (round-indexing it costs 9.6 MB).
//  - Slots are 128B-aligned and slot-disjoint at line granularity, so no
//    cache line spans two rounds' data.
__global__ __launch_bounds__(BT, 2) void nas_persist(
    const int* __restrict__ input_id, const float* __restrict__ emb,
    const float* __restrict__ Wih1, const float* __restrict__ Whh1,
    const float* __restrict__ bih1, const float* __restrict__ bhh1,
    const float* __restrict__ Wih2, const float* __restrict__ Whh2,
    const float* __restrict__ bih2, const float* __restrict__ bhh2,
    const float* __restrict__ Wout, const float* __restrict__ bout,
    float* __restrict__ out, float* __restrict__ ws)
{
    const int b = blockIdx.x, tid = threadIdx.x;
    const int wave = tid >> 6, lane = tid & 63;

    unsigned* flags = (unsigned*)ws + 4096;
    float* h2g    = ws + H2_W;            // [slot*H + i]
    float* logitp = ws + LOG_W;           // [slot*S*NB + s*NB + b]
    float* candp[2] = { ws + CAND_W, ws + CAND_W + S * H };
    float* xw1g = ws + XW1_W + (size_t)b * (V * ROWS);

    extern __shared__ char dyn_lds[];
    float4* whh2s = (float4*)dyn_lds;                 // [lane*145 + row*6 + j]
    float*  hbuf  = (float*)(dyn_lds + WHH2_B);       // chunked, stride 28

    __shared__ float gacc1[ROWS], g2f[ROWS], bsum2[ROWS], zlog[S], h2f[JPB];
    __shared__ float c1s[JPB], c2s[JPB], c1cand[S * JPB];
    __shared__ int   xid_s, pred_s;

    unsigned gen = 0;

    // ---------------- prologue ----------------
    if (tid < JPB) { c2s[tid] = 0.f; GST(h2g + b * JPB + tid, 0.f); }  // slot 0
    if (tid < ROWS) {
        int r = (tid / JPB) * H + b * JPB + (tid % JPB);
        bsum2[tid] = bih2[r] + bhh2[r];
    }
    if (tid == 0) xid_s = *input_id;

    // ---- xw1 table -> global ws (uses whh2s region as emb staging) ----
    {
        const int k0 = wave * RPW;
        float4 wiA[RPW], wiB[RPW];
        float  bs[RPW];
#pragma unroll
        for (int i = 0; i < RPW; ++i) {
            int k = k0 + i;
            int r = (k / JPB) * H + b * JPB + (k % JPB);
            const float4* w = (const float4*)(Wih1 + (size_t)r * E);
            wiA[i] = w[lane]; wiB[i] = w[lane + 64];
            bs[i]  = bih1[r] + bhh1[r];
        }
        float4* stage = (float4*)dyn_lds;             // 2048 f4 = 32 KB
        for (int ch = 0; ch < 8; ++ch) {
            const float4* src = (const float4*)(emb + (size_t)ch * 16 * E);
            for (int m = tid; m < 2048; m += BT) stage[m] = src[m];
            __syncthreads();
            for (int vv = 0; vv < 16; ++vv) {
                float4 ea = stage[vv * 128 + lane];
                float4 eb = stage[vv * 128 + 64 + lane];
#pragma unroll
                for (int i = 0; i < RPW; ++i) {
                    float a = wiA[i].x * ea.x + wiA[i].y * ea.y + wiA[i].z * ea.z + wiA[i].w * ea.w
                            + wiB[i].x * eb.x + wiB[i].y * eb.y + wiB[i].z * eb.z + wiB[i].w * eb.w;
                    a = wred(a);
                    if (lane == 0) xw1g[(ch * 16 + vv) * ROWS + (k0 + i)] = a + bs[i];
                }
            }
            __syncthreads();
        }
    }

    // ---- Whh2 -> LDS (lane-chunked, odd-f4 stride 145) ----
    for (int k = 0; k < ROWS; ++k) {
        int r = (k / JPB) * H + b * JPB + (k % JPB);
        const float4* src = (const float4*)(Whh2 + (size_t)r * H);
        if (tid < 384) {
            int l = tid / 6, j = tid % 6;
            whh2s[l * 145 + k * 6 + j] = src[tid];
        }
    }
    __syncthreads();

    // ---- Whh1 + Wih2 rows -> registers ----
    float w1[RPW][CHK], w2[RPW][CHK];
#pragma unroll
    for (int i = 0; i < RPW; ++i) {
        int k = wave * RPW + i;
        int r = (k / JPB) * H + b * JPB + (k % JPB);
        const float4* p1 = (const float4*)(Whh1 + (size_t)r * H) + lane * 6;
        const float4* p2 = (const float4*)(Wih2 + (size_t)r * H) + lane * 6;
#pragma unroll
        for (int j = 0; j < 6; ++j) {
            float4 v1 = p1[j], v2 = p2[j];
            w1[i][4 * j + 0] = v1.x; w1[i][4 * j + 1] = v1.y;
            w1[i][4 * j + 2] = v1.z; w1[i][4 * j + 3] = v1.w;
            w2[i][4 * j + 0] = v2.x; w2[i][4 * j + 1] = v2.y;
            w2[i][4 * j + 2] = v2.z; w2[i][4 * j + 3] = v2.w;
        }
    }
    __syncthreads();

    // ---- h1(0) from xid(0)=input_id (gacc1=0, c1(-1)=0); publish to slot 0 ----
    if (tid < JPB) {
        const float* xr = xw1g + (size_t)xid_s * ROWS;
        float gi = xr[tid], gg = xr[2 * JPB + tid], go = xr[3 * JPB + tid];
        float cn = sigf(gi) * tanhf(gg);
        c1s[tid] = cn;
        GST(candp[0] + b * JPB + tid, sigf(go) * tanhf(cn));   // slot 0, parity 0
    }
    gbar(flags, gen);

    // precomputed hbuf scatter maps (stride-28 chunked layout)
    const int m0 = (tid / CHK) * 28 + (tid % CHK);
    const int m1 = ((tid + 512) / CHK) * 28 + ((tid + 512) % CHK);
    const int m2 = ((tid + 1024) / CHK) * 28 + ((tid + 1024) % CHK);

    // ---------------- main loop: ONE barrier per round ----------------
    for (int k = 0; k <= T; ++k) {
        // ---- phase 0: issue all independent loads early ----
        float wcol[JPB];                       // Wout column slice for THIS round's
        if (k < T && wave == 0 && lane < S) {  // producer-side partial logits (tail)
            const float* wp = Wout + ((size_t)k * S + lane) * H + b * JPB;
#pragma unroll
            for (int j = 0; j < JPB; ++j) wcol[j] = wp[j];
        }
        // h2(k-1) gather: PLAIN cached loads from round-slot k (virgin lines)
        const float* h2src = h2g + (size_t)k * H;
        float u0 = h2src[tid];
        float u1 = h2src[tid + 512];
        float u2 = h2src[tid + 1024];

        // logits(k-1) = deterministic fixed-order tree over 256 partials
        // (PLAIN cached loads from round-slot k)
        if (k > 0) {
            const float* lp = logitp + (size_t)k * (S * NB)
                              + (tid >> 4) * NB + (tid & 15) * 16;
            float acc = 0.f;
#pragma unroll
            for (int i = 0; i < 16; ++i) acc += lp[i];
#pragma unroll
            for (int off = 8; off; off >>= 1) acc += __shfl_down(acc, off, 16);
            if ((tid & 15) == 0)
                zlog[tid >> 4] = acc + bout[(size_t)(k - 1) * S + (tid >> 4)];
        }
        __syncthreads();
        if (k > 0) {
            if (wave == 0) {
                float z = (lane < S) ? zlog[lane] : -1e30f;
                float v = z; int idx = (lane < S) ? lane : 9999;
#pragma unroll
                for (int off = 32; off; off >>= 1) {
                    float ov = __shfl_xor(v, off); int oi = __shfl_xor(idx, off);
                    if (ov > v || (ov == v && oi < idx)) { v = ov; idx = oi; }
                }
                float e = (lane < S) ? expf(z - v) : 0.f;
#pragma unroll
                for (int off = 32; off; off >>= 1) e += __shfl_xor(e, off);
                if (lane == 0) pred_s = idx;
                if (b == 0 && lane < S) out[(size_t)(k - 1) * S + lane] = z - v - logf(e);
            }
            __syncthreads();
        }
        if (k == T) return;                    // out[T-1] written; done
        const int psel = (k > 0) ? pred_s : 0;
        if (k > 0 && tid < JPB) c1s[tid] = c1cand[psel * JPB + tid];   // c1(k) select

        // ---- phase 1: issue h1 gather NOW; h2 LDS hop + gaccH hide its latency ----
        const float* h1src = candp[k & 1] + (size_t)psel * H;
        float t0 = GLD(h1src + tid);
        float t1 = GLD(h1src + tid + 512);
        float t2 = GLD(h1src + tid + 1024);

        hbuf[m0] = u0; hbuf[m1] = u1; hbuf[m2] = u2;   // h2 -> LDS
        __syncthreads();
        float h2c[CHK];
        {
            const float4* hp = (const float4*)hbuf + lane * 7;
#pragma unroll
            for (int j = 0; j < 6; ++j) {
                float4 v = hp[j];
                h2c[4 * j + 0] = v.x; h2c[4 * j + 1] = v.y;
                h2c[4 * j + 2] = v.z; h2c[4 * j + 3] = v.w;
            }
        }
        // Whh2 @ h2(k-1) dots (registers; h1 gather in flight underneath)
        float ahv[RPW];
#pragma unroll
        for (int i = 0; i < RPW; ++i) {
            int kk = wave * RPW + i;
            const float4* wp = whh2s + lane * 145 + kk * 6;
            float ah = 0.f;
#pragma unroll
            for (int j = 0; j < 6; ++j) {
                float4 v = wp[j];
                ah += v.x * h2c[4 * j + 0] + v.y * h2c[4 * j + 1]
                    + v.z * h2c[4 * j + 2] + v.w * h2c[4 * j + 3];
            }
            ahv[i] = wred(ah);                 // valid at lane 0
        }
        __syncthreads();                       // hbuf free for h1
        hbuf[m0] = t0; hbuf[m1] = t1; hbuf[m2] = t2;
        __syncthreads();
        float h1c[CHK];
        {
            const float4* hp = (const float4*)hbuf + lane * 7;
#pragma unroll
            for (int j = 0; j < 6; ++j) {
                float4 v = hp[j];
                h1c[4 * j + 0] = v.x; h1c[4 * j + 1] = v.y;
                h1c[4 * j + 2] = v.z; h1c[4 * j + 3] = v.w;
            }
        }
        // D1: Whh1 @ h1(k), Wih2 @ h1(k) (register weights)
        float a1[RPW], a2[RPW];
#pragma unroll
        for (int i = 0; i < RPW; ++i) { a1[i] = 0.f; a2[i] = 0.f; }
#pragma unroll
        for (int kk = 0; kk < CHK; ++kk) {
            float h = h1c[kk];
#pragma unroll
            for (int i = 0; i < RPW; ++i) {
                a1[i] += w1[i][kk] * h;
                a2[i] += w2[i][kk] * h;
            }
        }
#pragma unroll
        for (int i = 0; i < RPW; ++i) {
            int kk = wave * RPW + i;
            float s1 = wred(a1[i]);
            float s2 = wred(a2[i]);
            if (lane == 0) {
                gacc1[kk] = s1;
                g2f[kk]   = s2 + ahv[i] + bsum2[kk];
            }
        }
        __syncthreads();

        // P2: h2(k) fragment -> publish to round-slot k+1 (+ keep in LDS)
        if (tid < JPB) {
            float gi = g2f[tid],           gf = g2f[JPB + tid];
            float gg = g2f[2 * JPB + tid], go = g2f[3 * JPB + tid];
            float cn = sigf(gf) * c2s[tid] + sigf(gi) * tanhf(gg);
            c2s[tid] = cn;
            float hn = sigf(go) * tanhf(cn);
            h2f[tid] = hn;
            GST(h2g + (size_t)(k + 1) * H + b * JPB + tid, hn);
        }
        // candidates for h1(k+1): all 32 possible preds; publish fragments
        if (tid < S * JPB) {
            int p = tid / JPB, j = tid % JPB;
            const float* xr = xw1g + (size_t)((k & 3) * S + p) * ROWS;
            float gi = gacc1[j]           + xr[j];
            float gf = gacc1[JPB + j]     + xr[JPB + j];
            float gg = gacc1[2 * JPB + j] + xr[2 * JPB + j];
            float go = gacc1[3 * JPB + j] + xr[3 * JPB + j];
            float cn = sigf(gf) * c1s[j] + sigf(gi) * tanhf(gg);
            c1cand[tid] = cn;
            GST(candp[(k + 1) & 1] + (size_t)p * H + b * JPB + j,
                sigf(go) * tanhf(cn));
        }
        __syncthreads();                       // h2f visible to wave 0
        // producer-side partial logits(k) -> round-slot k+1
        if (wave == 0 && lane < S) {
            float p = 0.f;
#pragma unroll
            for (int j = 0; j < JPB; ++j) p += wcol[j] * h2f[j];
            GST(logitp + (size_t)(k + 1) * (S * NB) + lane * NB + b, p);
        }
        gbar(flags, gen);
    }
}

extern "C" void kernel_launch(void* const* d_in, const int* in_sizes, int n_in,
                              void* d_out, int out_size, void* d_ws, size_t ws_size,
                              hipStream_t stream) {
    const int*   input_id = (const int*)d_in[0];
    const float* emb  = (const float*)d_in[1];
    const float* Wih1 = (const float*)d_in[2];
    const float* Whh1 = (const float*)d_in[3];
    const float* bih1 = (const float*)d_in[4];
    const float* bhh1 = (const float*)d_in[5];
    const float* Wih2 = (const float*)d_in[6];
    const float* Whh2 = (const float*)d_in[7];
    const float* bih2 = (const float*)d_in[8];
    const float* bhh2 = (const float*)d_in[9];
    const float* Wout = (const float*)d_in[10];
    const float* bout = (const float*)d_in[11];
    float* out = (float*)d_out;
    float* ws  = (float*)d_ws;

    init_kernel<<<1, 256, 0, stream>>>((unsigned*)ws);

    void* args[] = { (void*)&input_id, (void*)&emb,
                     (void*)&Wih1, (void*)&Whh1, (void*)&bih1, (void*)&bhh1,
                     (void*)&Wih2, (void*)&Whh2, (void*)&bih2, (void*)&bhh2,
                     (void*)&Wout, (void*)&bout, (void*)&out, (void*)&ws };
    hipLaunchCooperativeKernel((void*)nas_persist, dim3(NB), dim3(BT), args,
                               DYN_LDS, stream);
}